// Round 1
// baseline (1980.632 us; speedup 1.0000x reference)
//
#include <hip/hip_runtime.h>

#define HH 50
#define NG 200        // 4*H gates
#define NB 4          // batch elements per block
#define TT 512
#define NTH 256
#define S_H0_STRIDE 52   // padded to 16B-aligned rows (52*4=208=13*16)
#define S_IN1_STRIDE 100 // 100*4=400=25*16, 16B aligned

__device__ __forceinline__ float fast_sigmoid(float x) {
    x = fminf(fmaxf(x, -30.f), 30.f);
    return 1.f / (1.f + __expf(-x));
}
__device__ __forceinline__ float fast_tanh(float x) {
    x = fminf(fmaxf(x, -15.f), 15.f);
    float e = __expf(2.f * x);
    return (e - 1.f) / (e + 1.f);
}

__global__ __launch_bounds__(NTH, 2) void lstm_fused_fp32(
    const float* __restrict__ x,
    const float* __restrict__ W_ih0, const float* __restrict__ W_hh0,
    const float* __restrict__ b_ih0, const float* __restrict__ b_hh0,
    const float* __restrict__ W_ih1, const float* __restrict__ W_hh1,
    const float* __restrict__ b_ih1, const float* __restrict__ b_hh1,
    const float* __restrict__ fc_w, const float* __restrict__ fc_b,
    float* __restrict__ out)
{
    __shared__ float s_x[NB * TT * 3];          // staged input tile: 24 KB
    __shared__ float s_h0[NB * S_H0_STRIDE];    // layer0 h_prev
    __shared__ float s_in1[NB * S_IN1_STRIDE];  // [h1_t (50) | hB_prev (50)]
    __shared__ float s_g[NB * NG];              // gate preactivations

    const int tid = threadIdx.x;
    const int b0 = blockIdx.x * NB;

    // ---- stage x into LDS (coalesced), zero h states ----
    for (int i = tid; i < NB * TT * 3; i += NTH) {
        int bb = i / (TT * 3);
        int r  = i - bb * (TT * 3);
        s_x[i] = x[(size_t)(b0 + bb) * (TT * 3) + r];
    }
    for (int i = tid; i < NB * S_H0_STRIDE; i += NTH) s_h0[i] = 0.f;
    for (int i = tid; i < NB * S_IN1_STRIDE; i += NTH) s_in1[i] = 0.f;

    // ---- per-lane weight rows into registers (loaded once, reused 512 steps) ----
    const int j = tid;  // gate index, active when < 200
    float w0x0 = 0.f, w0x1 = 0.f, w0x2 = 0.f;
    float w0h[HH];
    float w1[2 * HH];
    float bias0 = 0.f, bias1 = 0.f;
    if (j < NG) {
        w0x0 = W_ih0[j * 3 + 0];
        w0x1 = W_ih0[j * 3 + 1];
        w0x2 = W_ih0[j * 3 + 2];
        #pragma unroll
        for (int k = 0; k < HH; ++k) w0h[k] = W_hh0[j * HH + k];
        #pragma unroll
        for (int k = 0; k < HH; ++k) w1[k] = W_ih1[j * HH + k];
        #pragma unroll
        for (int k = 0; k < HH; ++k) w1[HH + k] = W_hh1[j * HH + k];
        bias0 = b_ih0[j] + b_hh0[j];
        bias1 = b_ih1[j] + b_hh1[j];
    } else {
        #pragma unroll
        for (int k = 0; k < HH; ++k) w0h[k] = 0.f;
        #pragma unroll
        for (int k = 0; k < 2 * HH; ++k) w1[k] = 0.f;
    }

    // cell-update role: thread (cb, cu) owns c-state in registers
    const int cb = tid / HH;        // valid when tid < 200
    const int cu = tid - cb * HH;
    float c0 = 0.f, cB = 0.f;

    __syncthreads();

    for (int t = 0; t < TT; ++t) {
        // ======== layer0 matvec: g[b][j] = bias0 + W_ih0[j]·x_t[b] + W_hh0[j]·h0[b] ========
        if (j < NG) {
            float acc[NB];
            #pragma unroll
            for (int b = 0; b < NB; ++b) {
                const float* xb = &s_x[(b * TT + t) * 3];
                acc[b] = bias0 + w0x0 * xb[0] + w0x1 * xb[1] + w0x2 * xb[2];
            }
            #pragma unroll
            for (int kq = 0; kq < HH / 4; ++kq) {   // 12 quads = k 0..47
                #pragma unroll
                for (int b = 0; b < NB; ++b) {
                    const float4 h4 = *(const float4*)&s_h0[b * S_H0_STRIDE + kq * 4];
                    acc[b] += w0h[kq * 4 + 0] * h4.x + w0h[kq * 4 + 1] * h4.y
                            + w0h[kq * 4 + 2] * h4.z + w0h[kq * 4 + 3] * h4.w;
                }
            }
            #pragma unroll
            for (int b = 0; b < NB; ++b) {
                acc[b] += w0h[48] * s_h0[b * S_H0_STRIDE + 48]
                        + w0h[49] * s_h0[b * S_H0_STRIDE + 49];
                s_g[b * NG + j] = acc[b];
            }
        }
        __syncthreads();
        // ======== layer0 cell ========
        if (tid < NB * HH) {
            float gi = fast_sigmoid(s_g[cb * NG + cu]);
            float gf = fast_sigmoid(s_g[cb * NG + cu + HH]);
            float gg = fast_tanh  (s_g[cb * NG + cu + 2 * HH]);
            float go = fast_sigmoid(s_g[cb * NG + cu + 3 * HH]);
            c0 = gf * c0 + gi * gg;
            float h = go * fast_tanh(c0);
            s_h0[cb * S_H0_STRIDE + cu] = h;    // next-step layer0 input
            s_in1[cb * S_IN1_STRIDE + cu] = h;  // layer1 input this step
        }
        __syncthreads();
        // ======== layer1 matvec: g[b][j] = bias1 + W_ih1[j]·h1_t[b] + W_hh1[j]·hB[b] ========
        if (j < NG) {
            float acc[NB];
            #pragma unroll
            for (int b = 0; b < NB; ++b) acc[b] = bias1;
            #pragma unroll
            for (int kq = 0; kq < (2 * HH) / 4; ++kq) {  // 25 quads
                #pragma unroll
                for (int b = 0; b < NB; ++b) {
                    const float4 h4 = *(const float4*)&s_in1[b * S_IN1_STRIDE + kq * 4];
                    acc[b] += w1[kq * 4 + 0] * h4.x + w1[kq * 4 + 1] * h4.y
                            + w1[kq * 4 + 2] * h4.z + w1[kq * 4 + 3] * h4.w;
                }
            }
            #pragma unroll
            for (int b = 0; b < NB; ++b) s_g[b * NG + j] = acc[b];
        }
        __syncthreads();
        // ======== layer1 cell ========
        if (tid < NB * HH) {
            float gi = fast_sigmoid(s_g[cb * NG + cu]);
            float gf = fast_sigmoid(s_g[cb * NG + cu + HH]);
            float gg = fast_tanh  (s_g[cb * NG + cu + 2 * HH]);
            float go = fast_sigmoid(s_g[cb * NG + cu + 3 * HH]);
            cB = gf * cB + gi * gg;
            float h = go * fast_tanh(cB);
            s_in1[cb * S_IN1_STRIDE + HH + cu] = h;  // hB state
        }
        __syncthreads();
    }

    // ======== final FC: out[b] = hB[b] @ fc_w.T + fc_b ========
    if (tid < NB * 3) {
        int bb = tid / 3, o = tid - bb * 3;
        float accv = fc_b[o];
        #pragma unroll
        for (int u = 0; u < HH; ++u)
            accv += s_in1[bb * S_IN1_STRIDE + HH + u] * fc_w[o * HH + u];
        out[(size_t)(b0 + bb) * 3 + o] = accv;
    }
}

extern "C" void kernel_launch(void* const* d_in, const int* in_sizes, int n_in,
                              void* d_out, int out_size, void* d_ws, size_t ws_size,
                              hipStream_t stream) {
    const float* x     = (const float*)d_in[0];
    const float* W_ih0 = (const float*)d_in[1];
    const float* W_hh0 = (const float*)d_in[2];
    const float* b_ih0 = (const float*)d_in[3];
    const float* b_hh0 = (const float*)d_in[4];
    const float* W_ih1 = (const float*)d_in[5];
    const float* W_hh1 = (const float*)d_in[6];
    const float* b_ih1 = (const float*)d_in[7];
    const float* b_hh1 = (const float*)d_in[8];
    const float* fc_w  = (const float*)d_in[9];
    const float* fc_b  = (const float*)d_in[10];
    float* out = (float*)d_out;

    const int B = 2048;
    dim3 grid(B / NB), block(NTH);
    lstm_fused_fp32<<<grid, block, 0, stream>>>(
        x, W_ih0, W_hh0, b_ih0, b_hh0, W_ih1, W_hh1, b_ih1, b_hh1, fc_w, fc_b, out);
}